// Round 2
// baseline (79.165 us; speedup 1.0000x reference)
//
#include <hip/hip_runtime.h>

#define NQ 10
#define TS 10
#define DIM 1024
#define ND 1024

typedef _Float16 h4 __attribute__((ext_vector_type(4)));
typedef __fp16  p2 __attribute__((ext_vector_type(2)));   // cvt_pkrtz result type
typedef float f4 __attribute__((ext_vector_type(4)));

// D = A*B + C, 16x16x16 f16 -> f32 (layout facts verified in R12):
//   C/D: (row,col) at lane = col + 16*(row>>2), reg = row&3
//   A:   (m,k)     at lane = m  + 16*(k>>2),   slot = k&3
//   B:   (k,n)     at lane = n  + 16*(k>>2),   slot = k&3
// => a stored C-tile read as A gives its TRANSPOSE; read as B gives itself.
__device__ __forceinline__ f4 mfma16(h4 a, h4 b, f4 c) {
    return __builtin_amdgcn_mfma_f32_16x16x16f16(a, b, c, 0, 0, 0);
}
__device__ __forceinline__ h4 cvt_h4(f4 x) {
    p2 lo = __builtin_amdgcn_cvt_pkrtz(x[0], x[1]);
    p2 hi = __builtin_amdgcn_cvt_pkrtz(x[2], x[3]);
    h4 r; r[0] = lo[0]; r[1] = lo[1]; r[2] = hi[0]; r[3] = hi[1];
    return r;
}
// conditional sign flip via precomputed xor mask (exact, 1 v_xor)
__device__ __forceinline__ float xsgn(float v, unsigned m) {
    return __uint_as_float(__float_as_uint(v) ^ m);
}

// TWO waves per sample (R2): R1 was neutral because 1024 waves on 1024 SIMDs
// = 1 wave/SIMD -> zero TLP; measured ~8.4k cyc/step vs ~1.4k issue cycles
// means the kernel is exposed-latency-bound. Wave w owns tiles n = 2w+{0,1};
// the H-stage (which mixes all 4 col-tiles) exchanges tr/ti fragments via
// double-buffered LDS with ONE __syncthreads per step. Per-wave work ~0.6x,
// occupancy 2 waves/SIMD -> latency hiding.
__global__ __launch_bounds__(128, 2) void qsim_kernel(
    const float* __restrict__ re_in, const float* __restrict__ im_in,
    const float* __restrict__ phis, const float* __restrict__ gs,
    float* __restrict__ out)
{
    const int sample = blockIdx.x;
    const int tid  = threadIdx.x;
    const int wid  = tid >> 6;           // wave id: owns tiles n = 2*wid + m
    const int lane = tid & 63;
    const int quad = lane >> 4;
    const int cc = lane & 15;
    const int c3 = (cc >> 3) & 1, c2 = (cc >> 2) & 1, c1 = (cc >> 1) & 1, c0 = cc & 1;
    const int q1 = quad >> 1, q0 = quad & 1;

    // hoisted per-lane selection state
    const bool e31 = (c3 == q1);
    const bool e20 = (c2 == q0);
    const bool bc1 = (c1 != 0);
    const bool bc0 = (c0 != 0);
    const unsigned sg3 = c3 ? 0u : 0x80000000u;
    const unsigned sg2 = c2 ? 0u : 0x80000000u;

    __shared__ h4 xch[2][4][2][64];      // [buf][tile j][re/im][lane] = 8 KB
    __shared__ float nsh[2];

    const float* pr_in = re_in + sample * DIM;
    const float* pi_in = im_in + sample * DIM;
    const float* ph = phis + sample * (3 * NQ * TS);
    const float* gsp = gs + sample * TS;

    // ---- load owned tiles into fragment layout ----
    f4 Sr[2], Si[2];
    const int lbase = 256 * quad + cc;
    const int noff = 32 * wid;           // 16*n = 32*wid + 16*m
#pragma unroll
    for (int m = 0; m < 2; ++m)
#pragma unroll
        for (int s = 0; s < 4; ++s) {
            Sr[m][s] = pr_in[lbase + 64 * s + noff + 16 * m];
            Si[m][s] = pi_in[lbase + 64 * s + noff + 16 * m];
        }

    const float inv = 0.15811388300841897f;  // 1/(2*sqrt(10))
    float gk[TS];
#pragma unroll
    for (int t = 0; t < TS; ++t) gk[t] = -0.5f * (gsp[t] * inv);

    // ---- normalize: per-wave partial -> LDS combine ----
    float nrm = 0.f;
#pragma unroll
    for (int m = 0; m < 2; ++m)
#pragma unroll
        for (int s = 0; s < 4; ++s) nrm += Sr[m][s] * Sr[m][s] + Si[m][s] * Si[m][s];
#pragma unroll
    for (int off = 32; off >= 1; off >>= 1) nrm += __shfl_xor(nrm, off, 64);
    if (lane == 0) nsh[wid] = nrm;
    __syncthreads();
    const float scl = rsqrtf(nsh[0] + nsh[1]);
#pragma unroll
    for (int m = 0; m < 2; ++m) { Sr[m] *= scl; Si[m] *= scl; }

    // ---- static pairsum per owned element (n = 2*wid+m -> popc = wid+m) ----
    float psv[2][4];
    const int pbase = __popc(quad) + __popc(cc) + wid;
#pragma unroll
    for (int m = 0; m < 2; ++m)
#pragma unroll
        for (int s = 0; s < 4; ++s) {
            const int p = pbase + m + __popc(s);
            const int z = NQ - 2 * p;
            psv[m][s] = 0.5f * (float)(z * z - NQ);
        }
    const float fq1 = (float)q1, fq0 = (float)q0;
    const float fc3 = (float)c3, fc2 = (float)c2, fc1 = (float)c1, fc0 = (float)c0;
    const float fwid = (float)wid;

    f4 DCPv[2], DSPv[2];     // single-buffered: written in prep(t), read at top of t+1
    h4 gbb[2];               // double-buffered gate tiles
    h4 hbb[2][2][4];         // [buf][m][j]
    float bcur[NQ];

    // diag-trig for owned tiles only (8 sincos instead of 16)
    auto make_trig = [&](const float* v, float kcur) {
        float sv = 0.f;
#pragma unroll
        for (int i = 0; i < NQ; ++i) sv += v[i];
        float base = -0.5f * sv;
        base = fmaf(fq1, v[0], base); base = fmaf(fq0, v[1], base);
        base = fmaf(fc3, v[6], base); base = fmaf(fc2, v[7], base);
        base = fmaf(fc1, v[8], base); base = fmaf(fc0, v[9], base);
        base = fmaf(fwid, v[4], base);                 // n1-bit term (wave-uniform)
        const float addS[4] = {0.f, v[3], v[2], v[2] + v[3]};
#pragma unroll
        for (int m = 0; m < 2; ++m) {
            const float bm = base + (m ? v[5] : 0.f);  // n0-bit term
#pragma unroll
            for (int s = 0; s < 4; ++s) {
                const float phi = fmaf(kcur, psv[m][s], bm + addS[s]);
                float sp, cp;
                __sincosf(phi, &sp, &cp);
                DCPv[m][s] = cp;
                DSPv[m][s] = sp;
            }
        }
    };

    // gate tiles: full gb (needed by own G-stage), hb only for owned n
    auto make_tiles = [&](const float* th, h4& gbo, h4 (&hbo)[2][4]) {
        float C[NQ], S[NQ];
#pragma unroll
        for (int g = 0; g < NQ; ++g) {
            float sg, cg;
            __sincosf(0.5f * th[g], &sg, &cg);
            S[g] = sg; C[g] = cg;
        }
        // ---- row gate gbo (qubits 0-3) ----
        {
            const float g0 = e31 ? C[0] : xsgn(S[0], sg3);
            const float g1 = e20 ? C[1] : xsgn(S[1], sg2);
            const float f01 = g0 * g1;
            const float A0 = bc1 ? S[2] : C[2];
            const float A1 = bc1 ? C[2] : -S[2];
            const float B0 = bc0 ? S[3] : C[3];
            const float B1 = bc0 ? C[3] : -S[3];
            p2 lo = __builtin_amdgcn_cvt_pkrtz(f01 * A0 * B0, f01 * A0 * B1);
            p2 hi = __builtin_amdgcn_cvt_pkrtz(f01 * A1 * B0, f01 * A1 * B1);
            gbo[0] = lo[0]; gbo[1] = lo[1]; gbo[2] = hi[0]; gbo[3] = hi[1];
        }
        // ---- col gate hbo[m][j] for n = 2*wid+m (qubits 4-9) ----
        const float F67 = (e31 ? C[6] : xsgn(S[6], sg3)) * (e20 ? C[7] : xsgn(S[7], sg2));
        const float A0p = bc1 ? S[8] : C[8];
        const float A1p = bc1 ? C[8] : -S[8];
        const float B0p = bc0 ? S[9] : C[9];
        const float B1p = bc0 ? C[9] : -S[9];
        float W[4];
        W[0] = F67 * A0p * B0p; W[1] = F67 * A0p * B1p;
        W[2] = F67 * A1p * B0p; W[3] = F67 * A1p * B1p;
        // hsel(n1=wid, j1): j1=0 -> wid?S4:C4 ; j1=1 -> wid?C4:-S4  (wave-uniform)
        const float s4_0 = wid ? S[4] : C[4];
        const float s4_1 = wid ? C[4] : -S[4];
#pragma unroll
        for (int m = 0; m < 2; ++m) {
            // hsel(n0=m, j0) is compile-time per m
            const float s5_0 = m ? S[5] : C[5];
            const float s5_1 = m ? C[5] : -S[5];
#pragma unroll
            for (int j = 0; j < 4; ++j) {
                const float v45 = ((j >> 1) ? s4_1 : s4_0) * ((j & 1) ? s5_1 : s5_0);
                p2 lo = __builtin_amdgcn_cvt_pkrtz(v45 * W[0], v45 * W[1]);
                p2 hi = __builtin_amdgcn_cvt_pkrtz(v45 * W[2], v45 * W[3]);
                hbo[m][j][0] = lo[0]; hbo[m][j][1] = lo[1];
                hbo[m][j][2] = hi[0]; hbo[m][j][3] = hi[1];
            }
        }
    };

    // ---- prologue: step-0 prep ----
    {
        float phs0[30];
#pragma unroll
        for (int j = 0; j < 30; ++j) phs0[j] = ph[j];
        make_trig(&phs0[0], 0.f);               // v0 = a0 (b(-1)=0), k=0
        make_tiles(&phs0[10], gbb[0], hbb[0]);
#pragma unroll
        for (int i = 0; i < NQ; ++i) bcur[i] = phs0[20 + i];
    }

    const f4 zf4 = {0.f, 0.f, 0.f, 0.f};

#pragma unroll
    for (int tt = 0; tt < TS; ++tt) {
        const int cb = tt & 1, nb = cb ^ 1;

        // ---- A. issue next-step phi loads (consumed after the barrier) ----
        float pn[30];
        if (tt + 1 < TS) {
#pragma unroll
            for (int j = 0; j < 30; ++j) pn[j] = ph[30 * (tt + 1) + j];
        }

        // ---- B. boundary diagonal on owned tiles ----
#pragma unroll
        for (int m = 0; m < 2; ++m) {
            const f4 xr = Sr[m], xi = Si[m];
            Sr[m] = DCPv[m] * xr - DSPv[m] * xi;
            Si[m] = DSPv[m] * xr + DCPv[m] * xi;
        }

        // ---- C. G-stage on owned tiles ----
        h4 tr[2], ti[2];
#pragma unroll
        for (int m = 0; m < 2; ++m) {
            f4 Trm = mfma16(cvt_h4(Sr[m]), gbb[cb], zf4);
            f4 Tim = mfma16(cvt_h4(Si[m]), gbb[cb], zf4);
            tr[m] = cvt_h4(Trm);
            ti[m] = cvt_h4(Tim);
        }

        // ---- D. exchange write (dbuf -> one barrier per step suffices) ----
#pragma unroll
        for (int m = 0; m < 2; ++m) {
            xch[cb][2 * wid + m][0][lane] = tr[m];
            xch[cb][2 * wid + m][1][lane] = ti[m];
        }
        __syncthreads();

        // ---- E. read all four tiles ----
        h4 trA[4], tiA[4];
#pragma unroll
        for (int j = 0; j < 4; ++j) {
            trA[j] = xch[cb][j][0][lane];
            tiA[j] = xch[cb][j][1][lane];
        }

        // ---- F. prep step tt+1 into the other buffers (overlaps ds_read
        //         latency and fills MFMA gaps of the H-stage) ----
        if (tt + 1 < TS) {
            float vN[NQ];
#pragma unroll
            for (int i = 0; i < NQ; ++i) vN[i] = pn[i] + bcur[i];
            make_trig(vN, gk[tt]);
            make_tiles(&pn[10], gbb[nb], hbb[nb]);
#pragma unroll
            for (int i = 0; i < NQ; ++i) bcur[i] = pn[20 + i];
        } else {
            make_trig(bcur, gk[TS - 1]);   // trailing diagonal
        }

        // ---- G. H-stage for owned output tiles, chains split 2+2 ----
#pragma unroll
        for (int m = 0; m < 2; ++m) {
            f4 r0 = mfma16(trA[0], hbb[cb][m][0], zf4);
            r0 = mfma16(trA[1], hbb[cb][m][1], r0);
            f4 r1 = mfma16(trA[2], hbb[cb][m][2], zf4);
            r1 = mfma16(trA[3], hbb[cb][m][3], r1);
            f4 i0 = mfma16(tiA[0], hbb[cb][m][0], zf4);
            i0 = mfma16(tiA[1], hbb[cb][m][1], i0);
            f4 i1 = mfma16(tiA[2], hbb[cb][m][2], zf4);
            i1 = mfma16(tiA[3], hbb[cb][m][3], i1);
            Sr[m] = r0 + r1;
            Si[m] = i0 + i1;
        }
    }

    // ---- trailing diagonal ----
#pragma unroll
    for (int m = 0; m < 2; ++m) {
        const f4 xr = Sr[m], xi = Si[m];
        Sr[m] = DCPv[m] * xr - DSPv[m] * xi;
        Si[m] = DSPv[m] * xr + DCPv[m] * xi;
    }

    float* outr = out + sample * DIM;
    float* outi = out + ND * DIM + sample * DIM;
#pragma unroll
    for (int m = 0; m < 2; ++m)
#pragma unroll
        for (int s = 0; s < 4; ++s) {
            outr[lbase + 64 * s + noff + 16 * m] = Sr[m][s];
            outi[lbase + 64 * s + noff + 16 * m] = Si[m][s];
        }
}

extern "C" void kernel_launch(void* const* d_in, const int* in_sizes, int n_in,
                              void* d_out, int out_size, void* d_ws, size_t ws_size,
                              hipStream_t stream) {
    const float* re_in = (const float*)d_in[0];
    const float* im_in = (const float*)d_in[1];
    const float* phis  = (const float*)d_in[2];
    const float* gs    = (const float*)d_in[3];
    float* out = (float*)d_out;
    qsim_kernel<<<ND, 128, 0, stream>>>(re_in, im_in, phis, gs, out);
}